// Round 1
// baseline (145.916 us; speedup 1.0000x reference)
//
#include <hip/hip_runtime.h>
#include <stdint.h>

#define DM 1024
#define LS 2048
#define RMS_EPS 1.1920928955078125e-07f
#define S2 0.0029296875f   // BC_SCALE^2 = 3/1024, exact in fp32

typedef __attribute__((ext_vector_type(8))) short bf16x8;
typedef __attribute__((ext_vector_type(4))) float f32x4;

__device__ __forceinline__ unsigned short f2bf(float f) {
  uint32_t u = __builtin_bit_cast(uint32_t, f);
  u += 0x7FFFu + ((u >> 16) & 1u);   // round-to-nearest-even
  return (unsigned short)(u >> 16);
}

// ---------------------------------------------------------------------------
// K0: pack B (64x1024) and C (64x1024) fp32 -> stacked bf16 [128][1024]
// ---------------------------------------------------------------------------
__global__ __launch_bounds__(256) void k0_prep(const float* __restrict__ B,
                                               const float* __restrict__ C,
                                               unsigned short* __restrict__ Bbf) {
  int i4 = blockIdx.x * 256 + threadIdx.x;          // 0..32767 float4s
  const float4* src = (i4 < 16384) ? (const float4*)B : (const float4*)C;
  float4 v = src[i4 & 16383];
  ushort4 o;
  o.x = f2bf(v.x); o.y = f2bf(v.y); o.z = f2bf(v.z); o.w = f2bf(v.w);
  ((ushort4*)Bbf)[i4] = o;
}

// ---------------------------------------------------------------------------
// KF: fully fused per-l-tile kernel.
// grid 512 (XCD-swizzled -> (b, t0)), block 1024 (16 waves, 1 block/CU).
// Phase S: stage u[1024][t0-16..t0+16) as bf16 tile[128][32] (k1 transpose+XOR).
// Phase G: 16-wave MFMA GEMM [B;C](128x1024) @ tile -> Bu[32][68], Cu[16][68].
//          (waves wm>=4,wn==0 compute discarded Cu halo: 25% slack, uniform.)
// Phase B/C: Kw[t][j] = S2 * sum_n Cu[t][n] A^j[n] Bu[t-j][n]  (k23-proven).
// Phase D: conv(W=16) + u*D skip + RMSNorm(d) + store (k23-proven Phase D;
//          ss[16][260] LDS reduce replaced by __shfl_xor in-wave reduce).
// LDS: 64KB tile (union'd with Part/KwS/SS2/rsq) + Bu 8.5KB + Cu 4.25KB = 76.75KB.
// ---------------------------------------------------------------------------
__global__ __launch_bounds__(1024) void kf(const float* __restrict__ u,
                                           const unsigned short* __restrict__ Bbf,
                                           const float* __restrict__ A,
                                           const float* __restrict__ Dv,
                                           const float* __restrict__ nw,
                                           float* __restrict__ out) {
  const int wg  = blockIdx.x;
  const int nbx = (wg & 7) * 64 + (wg >> 3);  // XCD-chunked bijective swizzle
  const int b   = nbx >> 7;
  const int t0  = (nbx & 127) << 4;
  const int tid = threadIdx.x;
  const int lane = tid & 63;
  const int w    = tid >> 6;
  const float* ub = u + (size_t)b * DM * LS;
  float* ob = out + (size_t)b * DM * LS;

  __shared__ __align__(16) char SMEM[65536];
  __shared__ __align__(16) float Bu[32][68];   // [l-col][n], stride 68 (=4 mod 32)
  __shared__ __align__(16) float Cu[16][68];   // [own t][n]
  bf16x8 (*tile)[32] = (bf16x8 (*)[32])SMEM;           // 65536 B (Phase S/G)
  float (*Part)[20]  = (float (*)[20])SMEM;            // 20480 B (Phase B/C)
  float (*KwS)[20]   = (float (*)[20])(SMEM + 20480);  // 1280 B
  float (*SS2)[20]   = (float (*)[20])(SMEM + 21760);  // 1280 B
  float *rsq         = (float*)(SMEM + 23040);         // 64 B

  { // ---- Phase S: stage. wave w: col-half w>>3, k-slab w&7 (128 k rows). ----
    const int h16 = w >> 3;
    const int ks  = w & 7;
    const int tb  = lane >> 5;
    const int kg  = (lane >> 2) & 7;
    const int lq  = lane & 3;
    const int kbase = 128*ks + 64*tb + 8*kg;
    const int gcol  = t0 - 16 + 16*h16 + 4*lq;   // wave-uniform-ish sign
    float4 vv[8];
    if (gcol >= 0) {
      #pragma unroll
      for (int r = 0; r < 8; ++r)
        vv[r] = *(const float4*)(ub + (size_t)(kbase + r) * LS + gcol);
    } else {
      #pragma unroll
      for (int r = 0; r < 8; ++r) vv[r] = make_float4(0.f, 0.f, 0.f, 0.f);
    }
    const int k8 = 16*ks + 8*tb + kg;
    #pragma unroll
    for (int c = 0; c < 4; ++c) {
      union { bf16x8 v; unsigned short s[8]; } t8;
      #pragma unroll
      for (int r = 0; r < 8; ++r) t8.s[r] = f2bf(((const float*)&vv[r])[c]);
      tile[k8][16*h16 + ((4*lq + c) ^ (k8 & 3))] = t8.v;
    }
  }
  __syncthreads();

  { // ---- Phase G: wave w computes rows [16wm,16wm+16) x cols [16wn,16wn+16) ----
    const int nn = lane & 15, q = lane >> 4;
    const int wm = w & 7, wn = w >> 3;
    const unsigned short* arow = Bbf + (size_t)(16*wm + nn) * DM;
    f32x4 acc = {};
    #pragma unroll 4
    for (int it = 0; it < 32; ++it) {
      bf16x8 bfrag = tile[4*it + q][16*wn + (nn ^ q)];
      bf16x8 afrag = *(const bf16x8*)(arow + 32*it + 8*q);
      acc = __builtin_amdgcn_mfma_f32_16x16x32_bf16(afrag, bfrag, acc, 0, 0, 0);
    }
    // C/D layout: col = lane&15, row = 4*(lane>>4) + reg  (k1-proven)
    const int ucol = 16*wn + nn;          // l-local col 0..31
    const int bcr  = 16*wm + 4*q;         // [B;C] row base
    if (wm < 4)       *(f32x4*)&Bu[ucol][bcr]            = acc;   // B rows 0..63
    else if (wn == 1) *(f32x4*)&Cu[ucol - 16][bcr - 64]  = acc;   // C rows, own cols
  }
  __syncthreads();

  { // ---- Phase B: Kw partials. thread = (t:16, p:16, jq:4). ----
    const int t  = tid & 15;
    const int p  = (tid >> 4) & 15;
    const int jq = tid >> 8;                  // 0..3
    const float4 cu = *(const float4*)&Cu[t][4*p];
    const float4 aa = *(const float4*)(A + 4*p);
    // ap = A^(4*jq) via squaring chain (replaces k23's apow LDS table)
    float a2x = aa.x*aa.x, a2y = aa.y*aa.y, a2z = aa.z*aa.z, a2w = aa.w*aa.w;
    float a4x = a2x*a2x,  a4y = a2y*a2y,  a4z = a2z*a2z,  a4w = a2w*a2w;
    float a8x = a4x*a4x,  a8y = a4y*a4y,  a8z = a4z*a4z,  a8w = a4w*a4w;
    float acx = a8x*a4x,  acy = a8y*a4y,  acz = a8z*a4z,  acw = a8w*a4w;
    float apx = (jq==0)?1.f:(jq==1)?a4x:(jq==2)?a8x:acx;
    float apy = (jq==0)?1.f:(jq==1)?a4y:(jq==2)?a8y:acy;
    float apz = (jq==0)?1.f:(jq==1)?a4z:(jq==2)?a8z:acz;
    float apw = (jq==0)?1.f:(jq==1)?a4w:(jq==2)?a8w:acw;
    float pw0 = cu.x * S2 * apx;
    float pw1 = cu.y * S2 * apy;
    float pw2 = cu.z * S2 * apz;
    float pw3 = cu.w * S2 * apw;
    #pragma unroll
    for (int jj = 0; jj < 4; ++jj) {
      const int j = 4*jq + jj;
      const float4 b4 = *(const float4*)&Bu[16 + t - j][4*p];
      Part[16*j + t][p] = pw0*b4.x + pw1*b4.y + pw2*b4.z + pw3*b4.w;
      pw0 *= aa.x; pw1 *= aa.y; pw2 *= aa.z; pw3 *= aa.w;
    }
  }
  __syncthreads();
  if (tid < 256) {                            // ---- Phase C: reduce over p ----
    float s = 0.f;
    #pragma unroll
    for (int p4 = 0; p4 < 4; ++p4) {
      const float4 v = *(const float4*)&Part[tid][4*p4];
      s += (v.x + v.y) + (v.z + v.w);
    }
    KwS[tid & 15][tid >> 4] = s;
  }
  __syncthreads();

  // ---- Phase D: conv + RMS + store (k23-proven mapping) ----
  const int tg = tid & 3;
  const int dr = tid >> 2;                    // 0..255
  float kw[4][16];
  #pragma unroll
  for (int k = 0; k < 4; ++k)
    #pragma unroll
    for (int i = 0; i < 4; ++i)
      *(float4*)&kw[k][4*i] = *(const float4*)&KwS[4*tg + k][4*i];  // broadcast

  const int cbase = t0 - 16 + 4*tg;
  float y[4][4];
  float ps[4] = {0.f, 0.f, 0.f, 0.f};
  #pragma unroll 1
  for (int c = 0; c < 4; ++c) {
    const int d = dr + 256*c;
    const float* row = ub + (size_t)d * LS;   // L1/L2-hot: staged this tile above
    float wr[20];
    #pragma unroll
    for (int s5 = 0; s5 < 5; ++s5) {
      int g = cbase + 4*s5;
      float4 v = (g >= 0) ? *(const float4*)(row + g)
                          : make_float4(0.f, 0.f, 0.f, 0.f);
      wr[4*s5+0] = v.x; wr[4*s5+1] = v.y; wr[4*s5+2] = v.z; wr[4*s5+3] = v.w;
    }
    const float Dd = Dv[d];
    #pragma unroll
    for (int k = 0; k < 4; ++k) {
      float acc = wr[16 + k] * Dd;            // skip connection u*D
      #pragma unroll
      for (int j = 0; j < 16; ++j)
        acc = fmaf(kw[k][j], wr[16 + k - j], acc);
      y[c][k] = acc;
      ps[k] = fmaf(acc, acc, ps[k]);
    }
  }
  // in-wave reduce: sum ps over the 16 lanes sharing tg (lane bits 2..5)
  #pragma unroll
  for (int k = 0; k < 4; ++k) {
    ps[k] += __shfl_xor(ps[k], 4, 64);
    ps[k] += __shfl_xor(ps[k], 8, 64);
    ps[k] += __shfl_xor(ps[k], 16, 64);
    ps[k] += __shfl_xor(ps[k], 32, 64);
  }
  if (lane < 4) {                             // lane == tg holds t = 4*lane+k
    float4 o = make_float4(ps[0], ps[1], ps[2], ps[3]);
    *(float4*)&SS2[w][4*lane] = o;
  }
  __syncthreads();
  if (tid < 16) {
    float s = 0.f;
    #pragma unroll
    for (int ww = 0; ww < 16; ++ww) s += SS2[ww][tid];
    rsq[tid] = rsqrtf(s * (1.f/1024.f) + RMS_EPS);
  }
  __syncthreads();
  float rq[4];
  #pragma unroll
  for (int k = 0; k < 4; ++k) rq[k] = rsq[4*tg + k];
  #pragma unroll
  for (int c = 0; c < 4; ++c) {
    const int d = dr + 256*c;
    const float wn2 = nw[d];
    float4 o;
    o.x = y[c][0] * rq[0] * wn2;
    o.y = y[c][1] * rq[1] * wn2;
    o.z = y[c][2] * rq[2] * wn2;
    o.w = y[c][3] * rq[3] * wn2;
    *(float4*)(ob + (size_t)d * LS + t0 + 4*tg) = o;
  }
}

// ---------------------------------------------------------------------------
extern "C" void kernel_launch(void* const* d_in, const int* in_sizes, int n_in,
                              void* d_out, int out_size, void* d_ws, size_t ws_size,
                              hipStream_t stream) {
  // inputs: [0]=L(int,1), [1]=u, [2]=A, [3]=B, [4]=C, [5]=D, [6]=norm_w
  const float* u  = (const float*)d_in[1];
  const float* A  = (const float*)d_in[2];
  const float* B  = (const float*)d_in[3];
  const float* C  = (const float*)d_in[4];
  const float* Dv = (const float*)d_in[5];
  const float* nw = (const float*)d_in[6];
  float* out = (float*)d_out;

  unsigned short* Bbf = (unsigned short*)d_ws;   // 256 KB (BuCuT eliminated)

  k0_prep<<<dim3(128), dim3(256),  0, stream>>>(B, C, Bbf);
  kf     <<<dim3(512), dim3(1024), 0, stream>>>(u, Bbf, A, Dv, nw, out);
}

// Round 2
// 145.132 us; speedup vs baseline: 1.0054x; 1.0054x over previous
//
#include <hip/hip_runtime.h>
#include <stdint.h>

#define DM 1024
#define LS 2048
#define RMS_EPS 1.1920928955078125e-07f
#define S2 0.0029296875f   // BC_SCALE^2 = 3/1024, exact in fp32

typedef __attribute__((ext_vector_type(8))) short bf16x8;
typedef __attribute__((ext_vector_type(4))) float f32x4;

__device__ __forceinline__ unsigned short f2bf(float f) {
  uint32_t u = __builtin_bit_cast(uint32_t, f);
  u += 0x7FFFu + ((u >> 16) & 1u);   // round-to-nearest-even
  return (unsigned short)(u >> 16);
}

// ---------------------------------------------------------------------------
// K0: pack B (64x1024) and C (64x1024) fp32 -> stacked bf16 [128][1024]
// ---------------------------------------------------------------------------
__global__ __launch_bounds__(256) void k0_prep(const float* __restrict__ B,
                                               const float* __restrict__ C,
                                               unsigned short* __restrict__ Bbf) {
  int i4 = blockIdx.x * 256 + threadIdx.x;          // 0..32767 float4s
  const float4* src = (i4 < 16384) ? (const float4*)B : (const float4*)C;
  float4 v = src[i4 & 16383];
  ushort4 o;
  o.x = f2bf(v.x); o.y = f2bf(v.y); o.z = f2bf(v.z); o.w = f2bf(v.w);
  ((ushort4*)Bbf)[i4] = o;
}

// ---------------------------------------------------------------------------
// KF v2: fused per-l-tile kernel, register-pressure-fixed for 2 blocks/CU.
// grid 512 (XCD-swizzled -> (b, t0)), block 1024 (16 waves).
// Design target: total VGPR+AGPR <= 64/lane so 2 blocks (32 waves) co-reside
// and overlap each other's phase latencies.  Changes vs v1:
//  - Phase D reads kw from LDS in 4-reg chunks (kills the 64-reg kw array
//    that AGPR-spilled v1 down to 1 block/CU).
//  - y[4][4] lives in LDS (unions with the dead bf16 tile).
//  - Phase C removed: in-wave __shfl_xor reduction over n inside Phase B
//    (one fewer barrier, -20KB Part traffic).
//  - SS2/rsq overlay dead Cu.  LDS/block = 79,872 B -> 2 blocks/CU.
// ---------------------------------------------------------------------------
__global__ __launch_bounds__(1024) void kf(const float* __restrict__ u,
                                           const unsigned short* __restrict__ Bbf,
                                           const float* __restrict__ A,
                                           const float* __restrict__ Dv,
                                           const float* __restrict__ nw,
                                           float* __restrict__ out) {
  const int wg  = blockIdx.x;
  const int nbx = (wg & 7) * 64 + (wg >> 3);  // XCD-chunked bijective swizzle
  const int b   = nbx >> 7;
  const int t0  = (nbx & 127) << 4;
  const int tid = threadIdx.x;
  const int lane = tid & 63;
  const int w    = tid >> 6;
  const float* ub = u + (size_t)b * DM * LS;
  float* ob = out + (size_t)b * DM * LS;

  __shared__ __align__(16) char SMEM[65536];   // tile (S,G)  UNION  y_lds (D)
  __shared__ __align__(16) float Bu[32][68];   // [l-col][n]   (G -> B)
  __shared__ __align__(16) float Cu[16][68];   // [own t][n]   (G -> B); dead after B
  __shared__ __align__(16) float KwS[16][20];  // Kw[t][j]     (B -> D)
  bf16x8 (*tile)[32]  = (bf16x8 (*)[32])SMEM;
  float (*y_lds)[1024] = (float (*)[1024])SMEM;
  float (*SS2)[20] = (float (*)[20])Cu;        // overlay: Cu dead after Phase B
  float *rsq       = (float*)((char*)Cu + 1280);

  { // ---- Phase S: stage. wave w: col-half w>>3, k-slab w&7 (128 k rows). ----
    const int h16 = w >> 3;
    const int ks  = w & 7;
    const int tb  = lane >> 5;
    const int kg  = (lane >> 2) & 7;
    const int lq  = lane & 3;
    const int kbase = 128*ks + 64*tb + 8*kg;
    const int gcol  = t0 - 16 + 16*h16 + 4*lq;
    float4 vv[8];
    if (gcol >= 0) {
      #pragma unroll
      for (int r = 0; r < 8; ++r)
        vv[r] = *(const float4*)(ub + (size_t)(kbase + r) * LS + gcol);
    } else {
      #pragma unroll
      for (int r = 0; r < 8; ++r) vv[r] = make_float4(0.f, 0.f, 0.f, 0.f);
    }
    const int k8 = 16*ks + 8*tb + kg;
    #pragma unroll
    for (int c = 0; c < 4; ++c) {
      union { bf16x8 v; unsigned short s[8]; } t8;
      #pragma unroll
      for (int r = 0; r < 8; ++r) t8.s[r] = f2bf(((const float*)&vv[r])[c]);
      tile[k8][16*h16 + ((4*lq + c) ^ (k8 & 3))] = t8.v;
    }
  }
  __syncthreads();

  { // ---- Phase G: wave w: rows [16wm,16wm+16) x cols [16wn,16wn+16) ----
    const int nn = lane & 15, q = lane >> 4;
    const int wm = w & 7, wn = w >> 3;
    const unsigned short* arow = Bbf + (size_t)(16*wm + nn) * DM;
    f32x4 acc = {};
    #pragma unroll 4
    for (int it = 0; it < 32; ++it) {
      bf16x8 bfrag = tile[4*it + q][16*wn + (nn ^ q)];
      bf16x8 afrag = *(const bf16x8*)(arow + 32*it + 8*q);
      acc = __builtin_amdgcn_mfma_f32_16x16x32_bf16(afrag, bfrag, acc, 0, 0, 0);
    }
    // C/D layout: col = lane&15, row = 4*(lane>>4) + reg  (proven)
    const int ucol = 16*wn + nn;          // l-local col 0..31
    const int bcr  = 16*wm + 4*q;         // [B;C] row base
    if (wm < 4)       *(f32x4*)&Bu[ucol][bcr]            = acc;   // B rows 0..63
    else if (wn == 1) *(f32x4*)&Cu[ucol - 16][bcr - 64]  = acc;   // C rows, own cols
  }
  __syncthreads();

  { // ---- Phase B+C: Kw[t][j] with in-wave n-reduction. ----
    // lane: p = n-quad (bits 0-3), tl = t-low (bits 4-5); wave: jq = w&3, th = w>>2
    const int p  = lane & 15;
    const int tl = lane >> 4;
    const int jq = w & 3;
    const int t  = 4*(w >> 2) + tl;
    const float4 cu = *(const float4*)&Cu[t][4*p];
    const float4 aa = *(const float4*)(A + 4*p);
    // ap = A^(4*jq) via squaring chain (jq is wave-uniform)
    float a2x = aa.x*aa.x, a2y = aa.y*aa.y, a2z = aa.z*aa.z, a2w = aa.w*aa.w;
    float a4x = a2x*a2x,  a4y = a2y*a2y,  a4z = a2z*a2z,  a4w = a2w*a2w;
    float a8x = a4x*a4x,  a8y = a4y*a4y,  a8z = a4z*a4z,  a8w = a4w*a4w;
    float acx = a8x*a4x,  acy = a8y*a4y,  acz = a8z*a4z,  acw = a8w*a4w;
    float apx = (jq==0)?1.f:(jq==1)?a4x:(jq==2)?a8x:acx;
    float apy = (jq==0)?1.f:(jq==1)?a4y:(jq==2)?a8y:acy;
    float apz = (jq==0)?1.f:(jq==1)?a4z:(jq==2)?a8z:acz;
    float apw = (jq==0)?1.f:(jq==1)?a4w:(jq==2)?a8w:acw;
    float pw0 = cu.x * S2 * apx;
    float pw1 = cu.y * S2 * apy;
    float pw2 = cu.z * S2 * apz;
    float pw3 = cu.w * S2 * apw;
    #pragma unroll
    for (int jj = 0; jj < 4; ++jj) {
      const int j = 4*jq + jj;
      const float4 b4 = *(const float4*)&Bu[16 + t - j][4*p];
      float s = pw0*b4.x + pw1*b4.y + pw2*b4.z + pw3*b4.w;
      s += __shfl_xor(s, 1, 64);
      s += __shfl_xor(s, 2, 64);
      s += __shfl_xor(s, 4, 64);
      s += __shfl_xor(s, 8, 64);
      if (p == 0) KwS[t][j] = s;
      pw0 *= aa.x; pw1 *= aa.y; pw2 *= aa.z; pw3 *= aa.w;
    }
  }
  __syncthreads();

  // ---- Phase D: conv + RMS + store.  kw read from LDS in 4-reg chunks. ----
  const int tg = tid & 3;
  const int dr = tid >> 2;                    // 0..255
  const int cbase = t0 - 16 + 4*tg;
  float ps[4] = {0.f, 0.f, 0.f, 0.f};
  #pragma unroll 1
  for (int c = 0; c < 4; ++c) {
    const int d = dr + 256*c;
    const float* row = ub + (size_t)d * LS;   // L2-hot: staged in Phase S
    float wr[20];
    #pragma unroll
    for (int s5 = 0; s5 < 5; ++s5) {
      int g = cbase + 4*s5;
      float4 v = (g >= 0) ? *(const float4*)(row + g)
                          : make_float4(0.f, 0.f, 0.f, 0.f);
      wr[4*s5+0] = v.x; wr[4*s5+1] = v.y; wr[4*s5+2] = v.z; wr[4*s5+3] = v.w;
    }
    const float Dd = Dv[d];
    #pragma unroll
    for (int k = 0; k < 4; ++k) {
      f32x4 kv0 = *(const f32x4*)&KwS[4*tg + k][0];    // broadcast ds_read_b128
      f32x4 kv1 = *(const f32x4*)&KwS[4*tg + k][4];
      f32x4 kv2 = *(const f32x4*)&KwS[4*tg + k][8];
      f32x4 kv3 = *(const f32x4*)&KwS[4*tg + k][12];
      float acc = wr[16 + k] * Dd;            // skip connection u*D
      #pragma unroll
      for (int j = 0; j < 4; ++j)  acc = fmaf(kv0[j], wr[16 + k - j],      acc);
      #pragma unroll
      for (int j = 0; j < 4; ++j)  acc = fmaf(kv1[j], wr[16 + k - (j+4)],  acc);
      #pragma unroll
      for (int j = 0; j < 4; ++j)  acc = fmaf(kv2[j], wr[16 + k - (j+8)],  acc);
      #pragma unroll
      for (int j = 0; j < 4; ++j)  acc = fmaf(kv3[j], wr[16 + k - (j+12)], acc);
      y_lds[4*tg + k][d] = acc;
      ps[k] = fmaf(acc, acc, ps[k]);
    }
  }
  // in-wave reduce: sum ps over the 16 lanes sharing tg (lane bits 2..5)
  #pragma unroll
  for (int k = 0; k < 4; ++k) {
    ps[k] += __shfl_xor(ps[k], 4, 64);
    ps[k] += __shfl_xor(ps[k], 8, 64);
    ps[k] += __shfl_xor(ps[k], 16, 64);
    ps[k] += __shfl_xor(ps[k], 32, 64);
  }
  if (lane < 4) {                             // lane == tg holds t = 4*lane+k
    float4 o = make_float4(ps[0], ps[1], ps[2], ps[3]);
    *(float4*)&SS2[w][4*lane] = o;
  }
  __syncthreads();
  if (tid < 16) {
    float s = 0.f;
    #pragma unroll
    for (int ww = 0; ww < 16; ++ww) s += SS2[ww][tid];
    rsq[tid] = rsqrtf(s * (1.f/1024.f) + RMS_EPS);
  }
  __syncthreads();
  float rq[4];
  #pragma unroll
  for (int k = 0; k < 4; ++k) rq[k] = rsq[4*tg + k];
  #pragma unroll
  for (int c = 0; c < 4; ++c) {
    const int d = dr + 256*c;
    const float wn2 = nw[d];
    float4 o;
    o.x = y_lds[4*tg + 0][d] * rq[0] * wn2;
    o.y = y_lds[4*tg + 1][d] * rq[1] * wn2;
    o.z = y_lds[4*tg + 2][d] * rq[2] * wn2;
    o.w = y_lds[4*tg + 3][d] * rq[3] * wn2;
    *(float4*)(ob + (size_t)d * LS + t0 + 4*tg) = o;
  }
}

// ---------------------------------------------------------------------------
extern "C" void kernel_launch(void* const* d_in, const int* in_sizes, int n_in,
                              void* d_out, int out_size, void* d_ws, size_t ws_size,
                              hipStream_t stream) {
  // inputs: [0]=L(int,1), [1]=u, [2]=A, [3]=B, [4]=C, [5]=D, [6]=norm_w
  const float* u  = (const float*)d_in[1];
  const float* A  = (const float*)d_in[2];
  const float* B  = (const float*)d_in[3];
  const float* C  = (const float*)d_in[4];
  const float* Dv = (const float*)d_in[5];
  const float* nw = (const float*)d_in[6];
  float* out = (float*)d_out;

  unsigned short* Bbf = (unsigned short*)d_ws;   // 256 KB

  k0_prep<<<dim3(128), dim3(256),  0, stream>>>(B, C, Bbf);
  kf     <<<dim3(512), dim3(1024), 0, stream>>>(u, Bbf, A, Dv, nw, out);
}